// Round 4
// baseline (383.932 us; speedup 1.0000x reference)
//
#include <hip/hip_runtime.h>

#define NIN 10517

__device__ __forceinline__ float lrelu02(float x){ return x > 0.f ? x : 0.2f*x; }
__device__ __forceinline__ float fast_tanh(float x){ float e=__expf(2.f*x); return 1.f - 2.f/(e+1.f); }
__device__ __forceinline__ float fast_sig(float x){ return 1.f/(1.f+__expf(-x)); }

// full-wave sum of the two K-halves: lane l gets partial[l] + partial[l^32].
// Pure-VALU (v_permlane32_swap) instead of ds_permute-based __shfl_xor.
__device__ __forceinline__ float half_reduce(float a){
  float s;
  asm volatile("v_mov_b32 %0, %1\n\t"
               "v_permlane32_swap_b32 %0, %1\n\t"
               "v_add_f32 %0, %0, %1"
               : "=&v"(s), "+v"(a));
  return s;
}

// ---------------- K1a: FC (384->256, relu) + Wh0 (256->128) + s,d per head ----------------
__global__ __launch_bounds__(256) void k_fc_gat(const float* __restrict__ inputs,
    const float* __restrict__ fc_w, const float* __restrict__ fc_b,
    const float* __restrict__ gat_w, const float* __restrict__ a_src, const float* __restrict__ a_dst,
    float* __restrict__ wh0_ws, float* __restrict__ sd_ws)
{
  __shared__ float xin[16][384];
  __shared__ float xfc[16][256];
  __shared__ float wh[16][128];
  const int tid = threadIdx.x;
  const int bt0 = blockIdx.x * 16;
  for (int idx = tid; idx < 16*384; idx += 256) {
    int r = idx / 384, f = idx - r*384;
    xin[r][f] = inputs[(size_t)(bt0+r)*NIN + 10133 + f];
  }
  __syncthreads();
  {
    float acc[16];
    float bj = fc_b[tid];
    #pragma unroll
    for (int r=0;r<16;r++) acc[r] = bj;
    for (int f=0; f<384; f++) {
      float wf = fc_w[f*256 + tid];
      #pragma unroll
      for (int r=0;r<16;r++) acc[r] = fmaf(xin[r][f], wf, acc[r]);
    }
    #pragma unroll
    for (int r=0;r<16;r++) xfc[r][tid] = fmaxf(acc[r], 0.f);
  }
  __syncthreads();
  {
    const int j2 = tid & 127, r0 = (tid >> 7) * 8;
    float acc[8];
    #pragma unroll
    for (int r=0;r<8;r++) acc[r] = 0.f;
    for (int f=0; f<256; f++) {
      float wf = gat_w[f*128 + j2];
      #pragma unroll
      for (int r=0;r<8;r++) acc[r] = fmaf(xfc[r0+r][f], wf, acc[r]);
    }
    #pragma unroll
    for (int r=0;r<8;r++) {
      wh[r0+r][j2] = acc[r];
      wh0_ws[(size_t)(bt0+r0+r)*128 + j2] = acc[r];
    }
  }
  __syncthreads();
  if (tid < 128) {
    const int r = tid >> 3, h = (tid >> 1) & 3, w = tid & 1;
    const float* av = w ? a_dst : a_src;
    float acc = 0.f;
    #pragma unroll
    for (int d=0; d<32; d++) acc = fmaf(wh[r][h*32+d], av[h*32+d], acc);
    sd_ws[(size_t)(bt0+r)*8 + w*4 + h] = acc;
  }
}

// ---------------- K1b: adjacency stats + closed-form alpha + x_gat + gi (fused) ----------------
__global__ __launch_bounds__(256) void k_alpha_gi(const float* __restrict__ inputs,
    const float* __restrict__ wh0_ws, const float* __restrict__ sd_ws,
    const float* __restrict__ gru_wi, const float* __restrict__ gru_bi,
    float* __restrict__ gi_ws)
{
  __shared__ int cnt[100];
  __shared__ int a0f[100];
  __shared__ float alpha[4][100];
  __shared__ float wh0[128];
  __shared__ float sdl[8];
  __shared__ float xg[128];
  const int tid = threadIdx.x;
  const size_t bt = blockIdx.x;
  if (tid < 128) wh0[tid] = wh0_ws[bt*128 + tid];
  if (tid < 8) sdl[tid] = sd_ws[bt*8 + tid];
  const float* adj = inputs + bt*NIN + 132;
  const int wv = tid >> 6, lane = tid & 63;
  for (int i = wv; i < 100; i += 4) {
    float v0 = adj[i*100 + lane];
    int pred0 = (lane != 0) && ((v0 > 0.f) || (lane == i));
    unsigned long long b0 = __ballot(pred0);
    int pred1 = 0;
    if (lane < 36) {
      float v1 = adj[i*100 + 64 + lane];
      pred1 = (v1 > 0.f) || ((64 + lane) == i);
    }
    unsigned long long b1 = __ballot(pred1);
    if (lane == 0) {
      cnt[i] = __popcll(b0) + __popcll(b1);
      a0f[i] = (v0 > 0.f) ? 1 : 0;
    }
  }
  __syncthreads();
  for (int idx = tid; idx < 400; idx += 256) {
    int h = idx / 100, i = idx - h*100;
    float s = sdl[h], d = sdl[4+h];
    float a;
    if (i == 0) {
      float ea = __expf(lrelu02(s + d));
      float eb = __expf(lrelu02(s));
      a = ea / (ea + (float)cnt[0] * eb);
    } else if (a0f[i]) {
      float ed = __expf(lrelu02(d));
      a = ed / (ed + (float)cnt[i]);
    } else {
      a = 0.f;
    }
    alpha[h][i] = a;
  }
  __syncthreads();
  if (tid < 128) {
    const int h = tid >> 5;
    const float w = wh0[tid];
    float sum = 0.f;
    for (int i=0;i<100;i++) {
      float t = alpha[h][i] * w;
      sum += (t > 0.f) ? t : (__expf(t) - 1.f);  // elu
    }
    xg[tid] = sum * 0.01f;  // mean over N=100
  }
  __syncthreads();
  // gi = x_gat @ gru_wi + gru_bi (weights stream from L2)
  for (int jj = tid; jj < 384; jj += 256) {
    float acc = gru_bi[jj];
    for (int f=0; f<128; f++) acc = fmaf(xg[f], gru_wi[f*384 + jj], acc);
    gi_ws[bt*384 + jj] = acc;
  }
}

// ---------------- K2: RK4-ODE + GRU scan ----------------
// 256 threads (4 waves), one block per batch element, launch_bounds(256,1)
// -> 1 wave/SIMD -> 512-VGPR budget so ALL weights stay register-resident:
//   ode w1,w2 half-columns (64+64) + gru_wh rows j,j+128,j+256 half-K (3*64)
//   = 320 VGPRs of weights.
// Column j = wave*32 + (lane&31); K-half p = lane>>5. Dot-reduce = single
// v_permlane32_swap (VALU) instead of 2x ds_permute shfl. 9 barriers/step,
// 4 waves each. gi prefetched one step ahead; dt staged once; hs buffered in
// LDS and dumped at the end.
__global__ __launch_bounds__(256, 1) void k_rnn(const float* __restrict__ inputs,
    const float* __restrict__ h0,
    const float* __restrict__ ode_w1, const float* __restrict__ ode_b1,
    const float* __restrict__ ode_w2, const float* __restrict__ ode_b2,
    const float* __restrict__ gru_wh, const float* __restrict__ gru_bh,
    const float* __restrict__ gi_ws, float* __restrict__ hs_ws, float* __restrict__ hT_out)
{
  __shared__ __align__(16) float Abuf[128];
  __shared__ __align__(16) float Bbuf[128];
  __shared__ __align__(16) float Cbuf[128];
  __shared__ float dtbuf[64];
  __shared__ __align__(16) float hsbuf[64*128];
  const int tid = threadIdx.x;
  const int b = blockIdx.x;
  const int lane = tid & 63;
  const int j = (tid >> 6) * 32 + (lane & 31);   // output column (x2 replicated)
  const int p = lane >> 5;                        // K-half

  float w1h[64], w2h[64], wgA[64], wgB[64], wgC[64];
  #pragma unroll
  for (int k=0;k<64;k++) w1h[k] = ode_w1[(p*64+k)*128 + j];
  #pragma unroll
  for (int k=0;k<64;k++) w2h[k] = ode_w2[(p*64+k)*128 + j];
  #pragma unroll
  for (int k=0;k<64;k++) wgA[k] = gru_wh[(size_t)(p*64+k)*384 + j];
  #pragma unroll
  for (int k=0;k<64;k++) wgB[k] = gru_wh[(size_t)(p*64+k)*384 + j + 128];
  #pragma unroll
  for (int k=0;k<64;k++) wgC[k] = gru_wh[(size_t)(p*64+k)*384 + j + 256];
  const float b1 = ode_b1[j], b2 = ode_b2[j];
  const float bh0 = gru_bh[j], bh1 = gru_bh[j+128], bh2 = gru_bh[j+256];
  float h = h0[b*128 + j];
  if (tid < 64) dtbuf[tid] = inputs[((size_t)b*64 + tid)*NIN + 10132];
  if (p == 0) Cbuf[j] = h;
  const float* gib = gi_ws + (size_t)b*64*384 + j;
  float gir = gib[0], giz = gib[128], gin = gib[256];
  __syncthreads();

  auto mv = [&](const float* __restrict__ src, const float (&wq)[64], float bias)->float {
    const float4* s4 = reinterpret_cast<const float4*>(src + p*64);
    float a0=0.f,a1=0.f,a2=0.f,a3=0.f;
    #pragma unroll
    for (int q=0;q<16;q++){
      float4 hv = s4[q];
      a0 = fmaf(hv.x, wq[4*q+0], a0);
      a1 = fmaf(hv.y, wq[4*q+1], a1);
      a2 = fmaf(hv.z, wq[4*q+2], a2);
      a3 = fmaf(hv.w, wq[4*q+3], a3);
    }
    float a = half_reduce((a0+a1)+(a2+a3));
    return fast_tanh(a + bias);
  };

  for (int t=0; t<64; t++) {
    const float dt = dtbuf[t];
    float u, k1, k2, k3, k4;
    u  = mv(Cbuf, w1h, b1); if (!p) Abuf[j] = u;                      __syncthreads();
    k1 = mv(Abuf, w2h, b2); if (!p) Bbuf[j] = fmaf(0.5f*dt, k1, h);   __syncthreads();
    u  = mv(Bbuf, w1h, b1); if (!p) Abuf[j] = u;                      __syncthreads();
    k2 = mv(Abuf, w2h, b2); if (!p) Bbuf[j] = fmaf(0.5f*dt, k2, h);   __syncthreads();
    u  = mv(Bbuf, w1h, b1); if (!p) Abuf[j] = u;                      __syncthreads();
    k3 = mv(Abuf, w2h, b2); if (!p) Bbuf[j] = fmaf(dt, k3, h);        __syncthreads();
    u  = mv(Bbuf, w1h, b1); if (!p) Abuf[j] = u;                      __syncthreads();
    k4 = mv(Abuf, w2h, b2);
    const float h_ode = fmaf(dt*(1.f/6.f), (k1 + 2.f*k2) + (2.f*k3 + k4), h);
    if (!p) Bbuf[j] = h_ode;                                          __syncthreads();

    // prefetch next step's gi (consumed next iteration; covered by 8 phases)
    const int tn = (t < 63) ? (t+1) : t;
    const float* gnb = gib + (size_t)tn*384;
    const float ngr = gnb[0], ngz = gnb[128], ngn = gnb[256];

    // gh = h_ode @ gru_wh (register-resident, half-K per lane)
    const float4* h4 = reinterpret_cast<const float4*>(Bbuf + p*64);
    float g0=0.f, g1=0.f, g2=0.f;
    #pragma unroll
    for (int q=0;q<16;q++){
      float4 hv = h4[q];
      g0 = fmaf(hv.x, wgA[4*q+0], g0); g0 = fmaf(hv.y, wgA[4*q+1], g0);
      g0 = fmaf(hv.z, wgA[4*q+2], g0); g0 = fmaf(hv.w, wgA[4*q+3], g0);
      g1 = fmaf(hv.x, wgB[4*q+0], g1); g1 = fmaf(hv.y, wgB[4*q+1], g1);
      g1 = fmaf(hv.z, wgB[4*q+2], g1); g1 = fmaf(hv.w, wgB[4*q+3], g1);
      g2 = fmaf(hv.x, wgC[4*q+0], g2); g2 = fmaf(hv.y, wgC[4*q+1], g2);
      g2 = fmaf(hv.z, wgC[4*q+2], g2); g2 = fmaf(hv.w, wgC[4*q+3], g2);
    }
    g0 = half_reduce(g0);
    g1 = half_reduce(g1);
    g2 = half_reduce(g2);

    const float r = fast_sig(gir + g0 + bh0);
    const float z = fast_sig(giz + g1 + bh1);
    const float n = fast_tanh(gin + r*(g2 + bh2));
    h = (1.f - z)*n + z*h_ode;
    if (!p) { Cbuf[j] = h; hsbuf[t*128 + j] = h; }
    gir = ngr; giz = ngz; gin = ngn;
    __syncthreads();
  }
  if (!p) hT_out[b*128 + j] = h;
  // dump hs (hsbuf writes synced by loop-end barrier)
  const float4* hv4 = reinterpret_cast<const float4*>(hsbuf);
  float4* o4 = reinterpret_cast<float4*>(hs_ws + (size_t)b*64*128);
  for (int idx = tid; idx < 64*128/4; idx += 256) o4[idx] = hv4[idx];
}

// ---------------- K3: logits + mask + value ----------------
__global__ __launch_bounds__(256) void k_head(const float* __restrict__ hs_ws,
    const float* __restrict__ act_w, const float* __restrict__ act_b,
    const float* __restrict__ val_w, const float* __restrict__ val_b,
    const float* __restrict__ inputs, float* __restrict__ out_logits, float* __restrict__ out_val)
{
  __shared__ float xr[16][128];
  const int tid = threadIdx.x;
  const int bt0 = blockIdx.x * 16;
  for (int idx = tid; idx < 16*128; idx += 256) {
    int r = idx >> 7, f = idx & 127;
    xr[r][f] = hs_ws[(size_t)(bt0+r)*128 + f];
  }
  __syncthreads();
  if (tid < 132) {
    float acc[16];
    float bj = act_b[tid];
    #pragma unroll
    for (int r=0;r<16;r++) acc[r] = bj;
    for (int f=0; f<128; f++) {
      float wf = act_w[f*132 + tid];
      #pragma unroll
      for (int r=0;r<16;r++) acc[r] = fmaf(xr[r][f], wf, acc[r]);
    }
    #pragma unroll
    for (int r=0;r<16;r++) {
      float mval = inputs[(size_t)(bt0+r)*NIN + tid];
      out_logits[(size_t)(bt0+r)*132 + tid] = (mval == 0.f) ? -1e10f : acc[r];
    }
  } else if (tid >= 136 && tid < 152) {
    int r = tid - 136;
    float acc = val_b[0];
    for (int f=0; f<128; f++) acc = fmaf(xr[r][f], val_w[f], acc);
    out_val[bt0 + r] = acc;
  }
}

extern "C" void kernel_launch(void* const* d_in, const int* in_sizes, int n_in,
                              void* d_out, int out_size, void* d_ws, size_t ws_size,
                              hipStream_t stream) {
  (void)in_sizes; (void)n_in; (void)out_size; (void)ws_size;
  const float* inputs = (const float*)d_in[0];
  const float* h0     = (const float*)d_in[1];
  const float* fc_w   = (const float*)d_in[2];
  const float* fc_b   = (const float*)d_in[3];
  const float* gat_w  = (const float*)d_in[4];
  const float* a_src  = (const float*)d_in[5];
  const float* a_dst  = (const float*)d_in[6];
  const float* ode_w1 = (const float*)d_in[7];
  const float* ode_b1 = (const float*)d_in[8];
  const float* ode_w2 = (const float*)d_in[9];
  const float* ode_b2 = (const float*)d_in[10];
  const float* gru_wi = (const float*)d_in[11];
  const float* gru_wh = (const float*)d_in[12];
  const float* gru_bi = (const float*)d_in[13];
  const float* gru_bh = (const float*)d_in[14];
  const float* act_w  = (const float*)d_in[15];
  const float* act_b  = (const float*)d_in[16];
  const float* val_w  = (const float*)d_in[17];
  const float* val_b  = (const float*)d_in[18];

  float* ws   = (float*)d_ws;
  float* wh0  = ws;              // 2048*128 = 262144
  float* sd   = ws + 262144;     // 2048*8   = 16384
  float* gi   = ws + 278528;     // 2048*384 = 786432
  float* hs   = ws + 1064960;    // 2048*128 = 262144

  float* out        = (float*)d_out;
  float* out_logits = out;            // 2048*132
  float* out_hT     = out + 270336;   // 32*128
  float* out_val    = out + 274432;   // 2048

  k_fc_gat  <<<dim3(128),  dim3(256), 0, stream>>>(inputs, fc_w, fc_b, gat_w, a_src, a_dst, wh0, sd);
  k_alpha_gi<<<dim3(2048), dim3(256), 0, stream>>>(inputs, wh0, sd, gru_wi, gru_bi, gi);
  k_rnn     <<<dim3(32),   dim3(256), 0, stream>>>(inputs, h0, ode_w1, ode_b1, ode_w2, ode_b2,
                                                   gru_wh, gru_bh, gi, hs, out_hT);
  k_head    <<<dim3(128),  dim3(256), 0, stream>>>(hs, act_w, act_b, val_w, val_b, inputs,
                                                   out_logits, out_val);
}

// Round 5
// 307.311 us; speedup vs baseline: 1.2493x; 1.2493x over previous
//
#include <hip/hip_runtime.h>

#define NIN 10517

__device__ __forceinline__ float lrelu02(float x){ return x > 0.f ? x : 0.2f*x; }
__device__ __forceinline__ float fast_tanh(float x){ float e=__expf(2.f*x); return 1.f - 2.f/(e+1.f); }
__device__ __forceinline__ float fast_sig(float x){ return 1.f/(1.f+__expf(-x)); }

// Sum over the 4 K-quarter lanes (lane ^16 then ^32) entirely in the VALU:
// v_permlane16_swap_b32 + v_permlane32_swap_b32 (gfx950) replace the two
// ds_permute-based __shfl_xor (~240cy LDS-pipe) with ~8cy of VALU.
__device__ __forceinline__ float quarter_reduce(float a){
  float s;
  asm volatile("v_mov_b32 %0, %1\n\t"
               "v_permlane16_swap_b32 %0, %1\n\t"
               "v_add_f32 %1, %0, %1"
               : "=&v"(s), "+v"(a));
  asm volatile("v_mov_b32 %0, %1\n\t"
               "v_permlane32_swap_b32 %0, %1\n\t"
               "v_add_f32 %1, %0, %1"
               : "=&v"(s), "+v"(a));
  return a;
}

// ---------------- K1a: FC (384->256, relu) + Wh0 (256->128) + s,d per head ----------------
__global__ __launch_bounds__(256) void k_fc_gat(const float* __restrict__ inputs,
    const float* __restrict__ fc_w, const float* __restrict__ fc_b,
    const float* __restrict__ gat_w, const float* __restrict__ a_src, const float* __restrict__ a_dst,
    float* __restrict__ wh0_ws, float* __restrict__ sd_ws)
{
  __shared__ float xin[16][384];
  __shared__ float xfc[16][256];
  __shared__ float wh[16][128];
  const int tid = threadIdx.x;
  const int bt0 = blockIdx.x * 16;
  for (int idx = tid; idx < 16*384; idx += 256) {
    int r = idx / 384, f = idx - r*384;
    xin[r][f] = inputs[(size_t)(bt0+r)*NIN + 10133 + f];
  }
  __syncthreads();
  {
    float acc[16];
    float bj = fc_b[tid];
    #pragma unroll
    for (int r=0;r<16;r++) acc[r] = bj;
    for (int f=0; f<384; f++) {
      float wf = fc_w[f*256 + tid];
      #pragma unroll
      for (int r=0;r<16;r++) acc[r] = fmaf(xin[r][f], wf, acc[r]);
    }
    #pragma unroll
    for (int r=0;r<16;r++) xfc[r][tid] = fmaxf(acc[r], 0.f);
  }
  __syncthreads();
  {
    const int j2 = tid & 127, r0 = (tid >> 7) * 8;
    float acc[8];
    #pragma unroll
    for (int r=0;r<8;r++) acc[r] = 0.f;
    for (int f=0; f<256; f++) {
      float wf = gat_w[f*128 + j2];
      #pragma unroll
      for (int r=0;r<8;r++) acc[r] = fmaf(xfc[r0+r][f], wf, acc[r]);
    }
    #pragma unroll
    for (int r=0;r<8;r++) {
      wh[r0+r][j2] = acc[r];
      wh0_ws[(size_t)(bt0+r0+r)*128 + j2] = acc[r];
    }
  }
  __syncthreads();
  if (tid < 128) {
    const int r = tid >> 3, h = (tid >> 1) & 3, w = tid & 1;
    const float* av = w ? a_dst : a_src;
    float acc = 0.f;
    #pragma unroll
    for (int d=0; d<32; d++) acc = fmaf(wh[r][h*32+d], av[h*32+d], acc);
    sd_ws[(size_t)(bt0+r)*8 + w*4 + h] = acc;
  }
}

// ---------------- K1b: adjacency stats + closed-form alpha + x_gat + gi (fused) ----------------
__global__ __launch_bounds__(256) void k_alpha_gi(const float* __restrict__ inputs,
    const float* __restrict__ wh0_ws, const float* __restrict__ sd_ws,
    const float* __restrict__ gru_wi, const float* __restrict__ gru_bi,
    float* __restrict__ gi_ws)
{
  __shared__ int cnt[100];
  __shared__ int a0f[100];
  __shared__ float alpha[4][100];
  __shared__ float wh0[128];
  __shared__ float sdl[8];
  __shared__ float xg[128];
  const int tid = threadIdx.x;
  const size_t bt = blockIdx.x;
  if (tid < 128) wh0[tid] = wh0_ws[bt*128 + tid];
  if (tid < 8) sdl[tid] = sd_ws[bt*8 + tid];
  const float* adj = inputs + bt*NIN + 132;
  const int wv = tid >> 6, lane = tid & 63;
  for (int i = wv; i < 100; i += 4) {
    float v0 = adj[i*100 + lane];
    int pred0 = (lane != 0) && ((v0 > 0.f) || (lane == i));
    unsigned long long b0 = __ballot(pred0);
    int pred1 = 0;
    if (lane < 36) {
      float v1 = adj[i*100 + 64 + lane];
      pred1 = (v1 > 0.f) || ((64 + lane) == i);
    }
    unsigned long long b1 = __ballot(pred1);
    if (lane == 0) {
      cnt[i] = __popcll(b0) + __popcll(b1);
      a0f[i] = (v0 > 0.f) ? 1 : 0;
    }
  }
  __syncthreads();
  for (int idx = tid; idx < 400; idx += 256) {
    int h = idx / 100, i = idx - h*100;
    float s = sdl[h], d = sdl[4+h];
    float a;
    if (i == 0) {
      float ea = __expf(lrelu02(s + d));
      float eb = __expf(lrelu02(s));
      a = ea / (ea + (float)cnt[0] * eb);
    } else if (a0f[i]) {
      float ed = __expf(lrelu02(d));
      a = ed / (ed + (float)cnt[i]);
    } else {
      a = 0.f;
    }
    alpha[h][i] = a;
  }
  __syncthreads();
  if (tid < 128) {
    const int h = tid >> 5;
    const float w = wh0[tid];
    float sum = 0.f;
    for (int i=0;i<100;i++) {
      float t = alpha[h][i] * w;
      sum += (t > 0.f) ? t : (__expf(t) - 1.f);  // elu
    }
    xg[tid] = sum * 0.01f;  // mean over N=100
  }
  __syncthreads();
  for (int jj = tid; jj < 384; jj += 256) {
    float acc = gru_bi[jj];
    for (int f=0; f<128; f++) acc = fmaf(xg[f], gru_wi[f*384 + jj], acc);
    gi_ws[bt*384 + jj] = acc;
  }
}

// ---------------- K2: RK4-ODE + GRU scan ----------------
// Round-3 shape (proven fastest): 512 threads (8 waves, 2/SIMD), one block
// per batch element. Column j = wave*16 + (lane&15); K-quarter p4.
// Fixes vs round 3:
//  * quarter_reduce: permlane16/32_swap (VALU) replaces 2x ds_permute shfl.
//  * weights pinned live via asm "+v" after load -> compiler cannot
//    rematerialize the per-step L2 reloads (round3 VGPR=104 showed it did).
//  * __launch_bounds__(512,2): 256-VGPR budget, 2 waves/SIMD preserved.
__global__ __launch_bounds__(512, 2) void k_rnn(const float* __restrict__ inputs,
    const float* __restrict__ h0,
    const float* __restrict__ ode_w1, const float* __restrict__ ode_b1,
    const float* __restrict__ ode_w2, const float* __restrict__ ode_b2,
    const float* __restrict__ gru_wh, const float* __restrict__ gru_bh,
    const float* __restrict__ gi_ws, float* __restrict__ hs_ws, float* __restrict__ hT_out)
{
  __shared__ __align__(16) float Abuf[144];
  __shared__ __align__(16) float Bbuf[144];
  __shared__ __align__(16) float Cbuf[144];
  __shared__ float dtbuf[64];
  __shared__ __align__(16) float hsbuf[64*128];
  const int tid = threadIdx.x;
  const int b = blockIdx.x;
  const int j  = ((tid >> 6) << 4) | (tid & 15);   // output column
  const int p4 = (tid >> 4) & 3;                    // K-quarter
  const int pj = ((j >> 5) * 36) + (j & 31);        // padded LDS index

  float w1q[32], w2q[32], wgA[32], wgB[32], wgC[32];
  #pragma unroll
  for (int k=0;k<32;k++) w1q[k] = ode_w1[(p4*32+k)*128 + j];
  #pragma unroll
  for (int k=0;k<32;k++) w2q[k] = ode_w2[(p4*32+k)*128 + j];
  #pragma unroll
  for (int k=0;k<32;k++) wgA[k] = gru_wh[(size_t)(p4*32+k)*384 + j];
  #pragma unroll
  for (int k=0;k<32;k++) wgB[k] = gru_wh[(size_t)(p4*32+k)*384 + j + 128];
  #pragma unroll
  for (int k=0;k<32;k++) wgC[k] = gru_wh[(size_t)(p4*32+k)*384 + j + 256];
  // pin: opaque in-place touch prevents rematerialization (forces residency)
  #pragma unroll
  for (int k=0;k<32;k++){
    asm volatile("" : "+v"(w1q[k]));
    asm volatile("" : "+v"(w2q[k]));
    asm volatile("" : "+v"(wgA[k]));
    asm volatile("" : "+v"(wgB[k]));
    asm volatile("" : "+v"(wgC[k]));
  }
  const float b1 = ode_b1[j], b2 = ode_b2[j];
  const float bh0 = gru_bh[j], bh1 = gru_bh[j+128], bh2 = gru_bh[j+256];
  float h = h0[b*128 + j];
  if (tid < 64) dtbuf[tid] = inputs[((size_t)b*64 + tid)*NIN + 10132];
  if (p4 == 0) Cbuf[pj] = h;
  const float* gib = gi_ws + (size_t)b*64*384 + j;
  float gir = gib[0], giz = gib[128], gin = gib[256];
  __syncthreads();

  auto mv = [&](const float* __restrict__ src, const float (&wq)[32], float bias)->float {
    const float4* s4 = reinterpret_cast<const float4*>(src + p4*36);
    float a0=0.f,a1=0.f,a2=0.f,a3=0.f;
    #pragma unroll
    for (int q=0;q<8;q++){
      float4 hv = s4[q];
      a0 = fmaf(hv.x, wq[4*q+0], a0);
      a1 = fmaf(hv.y, wq[4*q+1], a1);
      a2 = fmaf(hv.z, wq[4*q+2], a2);
      a3 = fmaf(hv.w, wq[4*q+3], a3);
    }
    float a = quarter_reduce((a0+a1)+(a2+a3));
    return fast_tanh(a + bias);
  };

  for (int t=0; t<64; t++) {
    const float dt = dtbuf[t];
    float u, k1, k2, k3, k4;
    u  = mv(Cbuf, w1q, b1); if (p4==0) Abuf[pj] = u;                      __syncthreads();
    k1 = mv(Abuf, w2q, b2); if (p4==0) Bbuf[pj] = fmaf(0.5f*dt, k1, h);   __syncthreads();
    u  = mv(Bbuf, w1q, b1); if (p4==0) Abuf[pj] = u;                      __syncthreads();
    k2 = mv(Abuf, w2q, b2); if (p4==0) Bbuf[pj] = fmaf(0.5f*dt, k2, h);   __syncthreads();
    u  = mv(Bbuf, w1q, b1); if (p4==0) Abuf[pj] = u;                      __syncthreads();
    k3 = mv(Abuf, w2q, b2); if (p4==0) Bbuf[pj] = fmaf(dt, k3, h);        __syncthreads();
    u  = mv(Bbuf, w1q, b1); if (p4==0) Abuf[pj] = u;                      __syncthreads();
    k4 = mv(Abuf, w2q, b2);
    const float h_ode = fmaf(dt*(1.f/6.f), (k1 + 2.f*k2) + (2.f*k3 + k4), h);
    if (p4==0) Bbuf[pj] = h_ode;                                          __syncthreads();

    // prefetch next step's gi under the gh phase
    const int tn = (t < 63) ? (t+1) : t;
    const float* gnb = gib + (size_t)tn*384;
    const float ngr = gnb[0], ngz = gnb[128], ngn = gnb[256];

    // gh = h_ode @ gru_wh (register-resident weights, quarter-K per lane)
    const float4* h4 = reinterpret_cast<const float4*>(Bbuf + p4*36);
    float g0=0.f, g1=0.f, g2=0.f;
    #pragma unroll
    for (int q=0;q<8;q++){
      float4 hv = h4[q];
      g0 = fmaf(hv.x, wgA[4*q+0], g0); g0 = fmaf(hv.y, wgA[4*q+1], g0);
      g0 = fmaf(hv.z, wgA[4*q+2], g0); g0 = fmaf(hv.w, wgA[4*q+3], g0);
      g1 = fmaf(hv.x, wgB[4*q+0], g1); g1 = fmaf(hv.y, wgB[4*q+1], g1);
      g1 = fmaf(hv.z, wgB[4*q+2], g1); g1 = fmaf(hv.w, wgB[4*q+3], g1);
      g2 = fmaf(hv.x, wgC[4*q+0], g2); g2 = fmaf(hv.y, wgC[4*q+1], g2);
      g2 = fmaf(hv.z, wgC[4*q+2], g2); g2 = fmaf(hv.w, wgC[4*q+3], g2);
    }
    g0 = quarter_reduce(g0);
    g1 = quarter_reduce(g1);
    g2 = quarter_reduce(g2);

    const float r = fast_sig(gir + g0 + bh0);
    const float z = fast_sig(giz + g1 + bh1);
    const float n = fast_tanh(gin + r*(g2 + bh2));
    h = (1.f - z)*n + z*h_ode;
    if (p4==0) { Cbuf[pj] = h; hsbuf[t*128 + j] = h; }
    gir = ngr; giz = ngz; gin = ngn;
    __syncthreads();
  }
  if (p4==0) hT_out[b*128 + j] = h;
  // dump hs (hsbuf writes synced by loop-end barrier)
  const float4* hv4 = reinterpret_cast<const float4*>(hsbuf);
  float4* o4 = reinterpret_cast<float4*>(hs_ws + (size_t)b*64*128);
  for (int idx = tid; idx < 64*128/4; idx += 512) o4[idx] = hv4[idx];
}

// ---------------- K3: logits + mask + value ----------------
__global__ __launch_bounds__(256) void k_head(const float* __restrict__ hs_ws,
    const float* __restrict__ act_w, const float* __restrict__ act_b,
    const float* __restrict__ val_w, const float* __restrict__ val_b,
    const float* __restrict__ inputs, float* __restrict__ out_logits, float* __restrict__ out_val)
{
  __shared__ float xr[16][128];
  const int tid = threadIdx.x;
  const int bt0 = blockIdx.x * 16;
  for (int idx = tid; idx < 16*128; idx += 256) {
    int r = idx >> 7, f = idx & 127;
    xr[r][f] = hs_ws[(size_t)(bt0+r)*128 + f];
  }
  __syncthreads();
  if (tid < 132) {
    float acc[16];
    float bj = act_b[tid];
    #pragma unroll
    for (int r=0;r<16;r++) acc[r] = bj;
    for (int f=0; f<128; f++) {
      float wf = act_w[f*132 + tid];
      #pragma unroll
      for (int r=0;r<16;r++) acc[r] = fmaf(xr[r][f], wf, acc[r]);
    }
    #pragma unroll
    for (int r=0;r<16;r++) {
      float mval = inputs[(size_t)(bt0+r)*NIN + tid];
      out_logits[(size_t)(bt0+r)*132 + tid] = (mval == 0.f) ? -1e10f : acc[r];
    }
  } else if (tid >= 136 && tid < 152) {
    int r = tid - 136;
    float acc = val_b[0];
    for (int f=0; f<128; f++) acc = fmaf(xr[r][f], val_w[f], acc);
    out_val[bt0 + r] = acc;
  }
}

extern "C" void kernel_launch(void* const* d_in, const int* in_sizes, int n_in,
                              void* d_out, int out_size, void* d_ws, size_t ws_size,
                              hipStream_t stream) {
  (void)in_sizes; (void)n_in; (void)out_size; (void)ws_size;
  const float* inputs = (const float*)d_in[0];
  const float* h0     = (const float*)d_in[1];
  const float* fc_w   = (const float*)d_in[2];
  const float* fc_b   = (const float*)d_in[3];
  const float* gat_w  = (const float*)d_in[4];
  const float* a_src  = (const float*)d_in[5];
  const float* a_dst  = (const float*)d_in[6];
  const float* ode_w1 = (const float*)d_in[7];
  const float* ode_b1 = (const float*)d_in[8];
  const float* ode_w2 = (const float*)d_in[9];
  const float* ode_b2 = (const float*)d_in[10];
  const float* gru_wi = (const float*)d_in[11];
  const float* gru_wh = (const float*)d_in[12];
  const float* gru_bi = (const float*)d_in[13];
  const float* gru_bh = (const float*)d_in[14];
  const float* act_w  = (const float*)d_in[15];
  const float* act_b  = (const float*)d_in[16];
  const float* val_w  = (const float*)d_in[17];
  const float* val_b  = (const float*)d_in[18];

  float* ws   = (float*)d_ws;
  float* wh0  = ws;              // 2048*128 = 262144
  float* sd   = ws + 262144;     // 2048*8   = 16384
  float* gi   = ws + 278528;     // 2048*384 = 786432
  float* hs   = ws + 1064960;    // 2048*128 = 262144

  float* out        = (float*)d_out;
  float* out_logits = out;            // 2048*132
  float* out_hT     = out + 270336;   // 32*128
  float* out_val    = out + 274432;   // 2048

  k_fc_gat  <<<dim3(128),  dim3(256), 0, stream>>>(inputs, fc_w, fc_b, gat_w, a_src, a_dst, wh0, sd);
  k_alpha_gi<<<dim3(2048), dim3(256), 0, stream>>>(inputs, wh0, sd, gru_wi, gru_bi, gi);
  k_rnn     <<<dim3(32),   dim3(512), 0, stream>>>(inputs, h0, ode_w1, ode_b1, ode_w2, ode_b2,
                                                   gru_wh, gru_bh, gi, hs, out_hT);
  k_head    <<<dim3(128),  dim3(256), 0, stream>>>(hs, act_w, act_b, val_w, val_b, inputs,
                                                   out_logits, out_val);
}